// Round 12
// baseline (79.803 us; speedup 1.0000x reference)
//
#include <hip/hip_runtime.h>
#include <math.h>

#define N 4096
#define D 64
#define NSLICE 8
#define JLEN 512          // N / NSLICE
#define CH 32             // j-chunk per iteration
#define NCHUNK 16         // JLEN / CH
#define SH 44.0f          // fixed softmax shift: exp(logit - 44); cancels in u/l

typedef short bf16x8 __attribute__((ext_vector_type(8)));
typedef float f32x4  __attribute__((ext_vector_type(4)));

__device__ __forceinline__ unsigned short f2bf(float x) {   // RNE f32->bf16
    unsigned int u = __float_as_uint(x);
    u += 0x7FFFu + ((u >> 16) & 1u);
    return (unsigned short)(u >> 16);
}
__device__ __forceinline__ float bf2f(unsigned short h) {
    return __uint_as_float(((unsigned int)h) << 16);
}

// Barrier that waits only LDS ops (used once, for the scl prologue).
__device__ __forceinline__ void lds_barrier() {
    asm volatile("s_waitcnt lgkmcnt(0)" ::: "memory");
    __builtin_amdgcn_s_barrier();
    asm volatile("" ::: "memory");
}
// Wave-local LDS fence: order ds_write -> ds_read within the wave.
__device__ __forceinline__ void wave_lds_fence() {
    asm volatile("s_waitcnt lgkmcnt(0)" ::: "memory");
}

// ---------------- Kernel A: per-row scale + Mt[d][j] = bf16(linear(msg)) ----------------
__global__ __launch_bounds__(256) void prep_kernel(
    const float* __restrict__ embed,
    const float* __restrict__ degd, const float* __restrict__ degt,
    const float* __restrict__ W1, const float* __restrict__ b1,
    const float* __restrict__ W2, const float* __restrict__ b2,
    const float* __restrict__ W3, const float* __restrict__ b3,
    float* __restrict__ scale, unsigned short* __restrict__ Mt)
{
    const int rel = blockIdx.y;
    const float* W  = (rel == 0) ? W1 : (rel == 1 ? W2 : W3);
    const float* bb = (rel == 0) ? b1 : (rel == 1 ? b2 : b3);
    __shared__ float Wl[D][D + 1];
    __shared__ float xr[4][D];
    __shared__ unsigned short ot[4][D];   // staged Mt tile for coalesced write
    const int tid = threadIdx.x;
    for (int idx = tid; idx < D * D; idx += 256)
        Wl[idx >> 6][idx & 63] = W[idx];
    const int w = tid >> 6, d = tid & 63;
    const int i0 = blockIdx.x * 4;
    const int i = i0 + w;

    float msg, term, xsrc, dga, dgb;
    if (rel == 0) {
        float s = embed[(size_t)i * D + d];
        msg = s + s * s; term = s * msg; xsrc = msg;
        dga = degd[i]; dgb = degd[i];
    } else if (rel == 1) {
        float s = embed[(size_t)i * D + d];
        float t = embed[(size_t)(N + i) * D + d];
        msg = t + s * t; term = s * msg; xsrc = msg;
        dga = degd[i]; dgb = degt[i];
    } else {
        float t = embed[(size_t)(N + i) * D + d];
        msg = t + t * t; term = t * msg; xsrc = t;   // similar uses linear(task)!
        dga = degt[i]; dgb = degt[i];
    }
    float dot = term;
    #pragma unroll
    for (int mm = 1; mm < 64; mm <<= 1) dot += __shfl_xor(dot, mm);
    if (d == 0)
        scale[rel * N + i] = dot / (sqrtf(dga * dgb + 1e-8f) * 8.0f);  // sqrt(D)=8

    xr[w][d] = xsrc;
    __syncthreads();
    float o = bb[d];
    #pragma unroll 8
    for (int k = 0; k < D; ++k) o += xr[w][k] * Wl[d][k];
    ot[w][d] = f2bf(o);
    __syncthreads();
    // Mt[d][i0..i0+3]: 8B runs, one thread per d (wave 0 only)
    if (tid < 64) {
        union { unsigned short h[4]; uint2 v; } t;
        t.h[0] = ot[0][tid]; t.h[1] = ot[1][tid];
        t.h[2] = ot[2][tid]; t.h[3] = ot[3][tid];
        *(uint2*)&Mt[((size_t)rel * D + tid) * N + i0] = t.v;
    }
}

// ------------- Kernel B: fixed-shift softmax x (att @ M) via bf16 MFMA -------------
// WAVE-INDEPENDENT: each wave owns a 16-row x 64-col output tile over JLEN cols.
// No block barriers in the main loop (E is wave-local LDS; S per-lane global;
// Mt B-fragments direct global, L2-hot). Latency hidden by 24 waves/CU TLP.
__global__ __launch_bounds__(256, 6) void attn_kernel(
    const float* __restrict__ S0, const float* __restrict__ S1, const float* __restrict__ S2,
    const float* __restrict__ scale, const unsigned short* __restrict__ Mt,
    unsigned short* __restrict__ Up, float* __restrict__ lp)
{
    __shared__ float scl_l[JLEN];                       // 2 KB, block-shared (read-only)
    __shared__ __align__(16) char EW[4][2048];          // per-wave E tile (1 KB) + repack (2 KB)
    const int rel = blockIdx.y, sl = blockIdx.z;
    const float* S = (rel == 0) ? S0 : (rel == 1 ? S1 : S2);
    const unsigned short* Mtr = Mt + (size_t)rel * D * N;
    const int tid = threadIdx.x;
    const int lane = tid & 63, wave = tid >> 6;
    const int rt = blockIdx.x * 4 + wave;               // this wave's 16-row tile
    const int j0 = sl * JLEN;

    // e-phase mapping: lane -> (r = lane>>2, q = lane&3); 8 cols per lane
    const int r = lane >> 2, q = lane & 3;
    const float* Sp = S + (size_t)(rt * 16 + r) * N + j0 + q * 8;

    // MFMA mapping
    const int lrow = lane & 15, lk = lane >> 4;
    const unsigned short* Bp = Mtr + (size_t)lrow * N + j0 + lk * 8;

    char* Ew = EW[wave];
    const int ewb  = q * 256 + ((r ^ q) << 4);          // E write slot (conflict-free)
    const int earb = lk * 256 + ((lrow ^ lk) << 4);     // E A-read slot (conflict-free)

    // prologue: stage scale slice (the only block barrier)
    for (int k = tid; k < JLEN; k += 256)
        scl_l[k] = scale[rel * N + j0 + k];
    lds_barrier();

    float l = 0.f;
    f32x4 acc[4];
    #pragma unroll
    for (int ct = 0; ct < 4; ++ct) {
        acc[ct][0] = 0.f; acc[ct][1] = 0.f; acc[ct][2] = 0.f; acc[ct][3] = 0.f;
    }

    #pragma unroll
    for (int c = 0; c < NCHUNK; ++c) {
        // ---- per-lane S loads + exp + pack -> wave-local E ----
        const f32x4 sa = *(const f32x4*)(Sp + c * CH);
        const f32x4 sb = *(const f32x4*)(Sp + c * CH + 4);
        const f32x4 ca = *(const f32x4*)&scl_l[c * CH + q * 8];
        const f32x4 cb = *(const f32x4*)&scl_l[c * CH + q * 8 + 4];
        float e[8];
        #pragma unroll
        for (int u = 0; u < 4; ++u) {
            e[u]     = __expf(fmaf(sa[u], ca[u], -SH));
            e[4 + u] = __expf(fmaf(sb[u], cb[u], -SH));
        }
        #pragma unroll
        for (int k = 0; k < 8; ++k) l += e[k];
        union { unsigned short h[8]; uint4 v; } pk;
        #pragma unroll
        for (int k = 0; k < 8; ++k) pk.h[k] = f2bf(e[k]);
        *(uint4*)(Ew + ewb) = pk.v;

        wave_lds_fence();   // wave-local: write visible to this wave's reads

        // ---- MFMA: A from wave-local E, B direct from global Mt (L2-hot) ----
        const bf16x8 a = *(const bf16x8*)(Ew + earb);
        __builtin_amdgcn_s_setprio(1);
        #pragma unroll
        for (int ct = 0; ct < 4; ++ct) {
            const bf16x8 b = *(const bf16x8*)(Bp + (size_t)ct * 16 * N + c * CH);
            acc[ct] = __builtin_amdgcn_mfma_f32_16x16x32_bf16(a, b, acc[ct], 0, 0, 0);
        }
        __builtin_amdgcn_s_setprio(0);
        wave_lds_fence();   // A-read done before next chunk overwrites E
    }

    // ---- epilogue: repack 16x64 bf16 tile via wave LDS, coalesced 2 KB store ----
    unsigned short* Rw = (unsigned short*)Ew;
    #pragma unroll
    for (int ct = 0; ct < 4; ++ct)
        #pragma unroll
        for (int rr = 0; rr < 4; ++rr) {
            const int row = lk * 4 + rr;        // C/D: row=(lane>>4)*4+reg, col=ct*16+(lane&15)
            Rw[row * 64 + ct * 16 + lrow] = f2bf(acc[ct][rr]);
        }
    wave_lds_fence();
    const size_t pbase = (size_t)((rel * 256 + rt) * NSLICE + sl);
    unsigned short* up = Up + pbase * 1024;
    *(uint4*)&up[r * 64 + q * 16]     = *(const uint4*)&Rw[r * 64 + q * 16];
    *(uint4*)&up[r * 64 + q * 16 + 8] = *(const uint4*)&Rw[r * 64 + q * 16 + 8];

    // per-row l: reduce the 4 q-partials
    l += __shfl_xor(l, 1);
    l += __shfl_xor(l, 2);
    if (q == 0) lp[pbase * 16 + r] = l;
}

// ---------------- Kernel C: combine partials + residual + linear(W3) + leaky-relu ----------------
__device__ __forceinline__ float combine_row(
    const unsigned short* __restrict__ Up, const float* __restrict__ lp,
    int rel, int i, int d)
{
    const int rt = i >> 4, r = i & 15;
    const int base = (rel * 256 + rt) * NSLICE;
    float lt = 0.f, u = 0.f;
    #pragma unroll
    for (int p = 0; p < NSLICE; ++p) {
        lt += lp[(base + p) * 16 + r];
        u  += bf2f(Up[(size_t)(base + p) * 1024 + r * 64 + d]);
    }
    return u / lt;   // fixed shift cancels; lt > 0 always
}

__global__ __launch_bounds__(256) void final_kernel(
    const float* __restrict__ embed,
    const unsigned short* __restrict__ Up, const float* __restrict__ lp,
    const float* __restrict__ W3, const float* __restrict__ b3,
    float* __restrict__ out)
{
    __shared__ float Wl[D][D + 1];
    __shared__ float xs[4][D];
    const int tid = threadIdx.x;
    for (int idx = tid; idx < D * D; idx += 256)
        Wl[idx >> 6][idx & 63] = W3[idx];
    const int w = tid >> 6, d = tid & 63;
    const int g = blockIdx.x * 4 + w;   // 0..8191

    float x = embed[(size_t)g * D + d];
    if (g < N) {
        x += combine_row(Up, lp, 0, g, d);
        x += combine_row(Up, lp, 1, g, d);
    } else {
        x += combine_row(Up, lp, 2, g - N, d);
    }
    xs[w][d] = x;
    __syncthreads();
    float o = b3[d];
    #pragma unroll 8
    for (int k = 0; k < D; ++k) o += xs[w][k] * Wl[d][k];
    o = (o > 0.f) ? o : 0.2f * o;
    out[(size_t)g * D + d] = o;
}

extern "C" void kernel_launch(void* const* d_in, const int* in_sizes, int n_in,
                              void* d_out, int out_size, void* d_ws, size_t ws_size,
                              hipStream_t stream)
{
    const float* embed = (const float*)d_in[0];
    // d_in[1..3] = adj_* (unused by the reference)
    const float* Sc   = (const float*)d_in[4];
    const float* Si   = (const float*)d_in[5];
    const float* Ss   = (const float*)d_in[6];
    const float* degd = (const float*)d_in[7];
    const float* degt = (const float*)d_in[8];
    const float* W1 = (const float*)d_in[9];
    const float* b1 = (const float*)d_in[10];
    const float* W2 = (const float*)d_in[11];
    const float* b2 = (const float*)d_in[12];
    const float* W3 = (const float*)d_in[13];
    const float* b3 = (const float*)d_in[14];
    float* out = (float*)d_out;

    // ws layout:
    //   scale: 3*N                 = 12288 f32
    //   lp:    3*256*NSLICE*16     = 98304 f32
    //   Mt:    3*D*N               = 786432 ushort
    //   Up:    3*256*NSLICE*1024   = 6291456 ushort        total ~14.6 MB
    float* ws    = (float*)d_ws;
    float* scale = ws;
    float* lp    = ws + 12288;
    unsigned short* Mt = (unsigned short*)(lp + 98304);
    unsigned short* Up = Mt + 786432;

    prep_kernel<<<dim3(N / 4, 3), 256, 0, stream>>>(
        embed, degd, degt, W1, b1, W2, b2, W3, b3, scale, Mt);
    attn_kernel<<<dim3(64, 3, NSLICE), 256, 0, stream>>>(
        Sc, Si, Ss, scale, Mt, Up, lp);
    final_kernel<<<dim3(2 * N / 4), 256, 0, stream>>>(
        embed, Up, lp, W3, b3, out);
}

// Round 13
// 71.060 us; speedup vs baseline: 1.1230x; 1.1230x over previous
//
#include <hip/hip_runtime.h>
#include <math.h>

#define N 4096
#define D 64
#define NSLICE 4
#define JLEN 1024         // N / NSLICE
#define CH 32             // j-chunk per iteration
#define NCHUNK 32         // JLEN / CH
#define SH 44.0f          // fixed softmax shift: exp(logit - 44); cancels in u/l

// LDS byte map (one 44 KB block):
//   S tiles:  3 x 8 KB  fp32 [64 rows][8 slots], slot XOR (row&7) via global pre-swizzle
//   Mt tiles: 3 x 4 KB  bf16, k-slot-major: slot n = lk*64 + d  (lane-consecutive MFMA B reads)
//   E tile:   4 KB      bf16, slot = q*64 + (row^2q)  (conflict-free write AND read)
//   scl:      4 KB      fp32 scale slice
#define S_OFF   0
#define MT_OFF  24576
#define E_OFF   36864
#define SCL_OFF 40960
#define LDS_BYTES 45056

typedef short bf16x8 __attribute__((ext_vector_type(8)));
typedef float f32x4  __attribute__((ext_vector_type(4)));

__device__ __forceinline__ unsigned short f2bf(float x) {   // RNE f32->bf16
    unsigned int u = __float_as_uint(x);
    u += 0x7FFFu + ((u >> 16) & 1u);
    return (unsigned short)(u >> 16);
}
__device__ __forceinline__ float bf2f(unsigned short h) {
    return __uint_as_float(((unsigned int)h) << 16);
}

// async global->LDS DMA, 16B per lane; LDS dest wave-uniform base + lane*16.
// aux: cache-policy bits (bit1 = nt / non-temporal on gfx950).
__device__ __forceinline__ void gld16(const void* g, void* l) {
    __builtin_amdgcn_global_load_lds(
        (const __attribute__((address_space(1))) void*)g,
        (__attribute__((address_space(3))) void*)l,
        16, 0, 0);
}
__device__ __forceinline__ void gld16_nt(const void* g, void* l) {
    __builtin_amdgcn_global_load_lds(
        (const __attribute__((address_space(1))) void*)g,
        (__attribute__((address_space(3))) void*)l,
        16, 0, 2);   // nt: streaming, minimal L2 retention
}

// Barrier that waits only LDS ops; global/DMA loads stay in flight across it.
__device__ __forceinline__ void lds_barrier() {
    asm volatile("s_waitcnt lgkmcnt(0)" ::: "memory");
    __builtin_amdgcn_s_barrier();
    asm volatile("" ::: "memory");
}
__device__ __forceinline__ void plain_barrier() {
    asm volatile("" ::: "memory");
    __builtin_amdgcn_s_barrier();
    asm volatile("" ::: "memory");
}

// ---------------- Kernel A: per-row scale + Mt[d][j] = bf16(linear(msg)) ----------------
__global__ __launch_bounds__(256) void prep_kernel(
    const float* __restrict__ embed,
    const float* __restrict__ degd, const float* __restrict__ degt,
    const float* __restrict__ W1, const float* __restrict__ b1,
    const float* __restrict__ W2, const float* __restrict__ b2,
    const float* __restrict__ W3, const float* __restrict__ b3,
    float* __restrict__ scale, unsigned short* __restrict__ Mt)
{
    const int rel = blockIdx.y;
    const float* W  = (rel == 0) ? W1 : (rel == 1 ? W2 : W3);
    const float* bb = (rel == 0) ? b1 : (rel == 1 ? b2 : b3);
    __shared__ float Wl[D][D + 1];
    __shared__ float xr[4][D];
    __shared__ unsigned short ot[4][D];   // staged Mt tile for coalesced write
    const int tid = threadIdx.x;
    for (int idx = tid; idx < D * D; idx += 256)
        Wl[idx >> 6][idx & 63] = W[idx];
    const int w = tid >> 6, d = tid & 63;
    const int i0 = blockIdx.x * 4;
    const int i = i0 + w;

    float msg, term, xsrc, dga, dgb;
    if (rel == 0) {
        float s = embed[(size_t)i * D + d];
        msg = s + s * s; term = s * msg; xsrc = msg;
        dga = degd[i]; dgb = degd[i];
    } else if (rel == 1) {
        float s = embed[(size_t)i * D + d];
        float t = embed[(size_t)(N + i) * D + d];
        msg = t + s * t; term = s * msg; xsrc = msg;
        dga = degd[i]; dgb = degt[i];
    } else {
        float t = embed[(size_t)(N + i) * D + d];
        msg = t + t * t; term = t * msg; xsrc = t;   // similar uses linear(task)!
        dga = degt[i]; dgb = degt[i];
    }
    float dot = term;
    #pragma unroll
    for (int mm = 1; mm < 64; mm <<= 1) dot += __shfl_xor(dot, mm);
    if (d == 0)
        scale[rel * N + i] = dot / (sqrtf(dga * dgb + 1e-8f) * 8.0f);  // sqrt(D)=8

    xr[w][d] = xsrc;
    __syncthreads();
    float o = bb[d];
    #pragma unroll 8
    for (int k = 0; k < D; ++k) o += xr[w][k] * Wl[d][k];
    ot[w][d] = f2bf(o);
    __syncthreads();
    // Mt[d][i0..i0+3]: 8B runs, one thread per d (wave 0 only)
    if (tid < 64) {
        union { unsigned short h[4]; uint2 v; } t;
        t.h[0] = ot[0][tid]; t.h[1] = ot[1][tid];
        t.h[2] = ot[2][tid]; t.h[3] = ot[3][tid];
        *(uint2*)&Mt[((size_t)rel * D + tid) * N + i0] = t.v;
    }
}

// ------------- Kernel B: fixed-shift softmax x (att @ M) via bf16 MFMA -------------
// grid (64 rowgroups, 3 rels, NSLICE slices), block 256 (4 waves), 3 blocks/CU.
// All staging via global_load_lds DMA into triple-buffered LDS tiles;
// counted s_waitcnt vmcnt(3) -- never drain to 0 in the main loop.
// S stream uses nt cache policy (zero reuse -> don't pollute L2).
__global__ __launch_bounds__(256, 3) void attn_kernel(
    const float* __restrict__ S0, const float* __restrict__ S1, const float* __restrict__ S2,
    const float* __restrict__ scale, const unsigned short* __restrict__ Mt,
    unsigned short* __restrict__ Up, float* __restrict__ lp)
{
    __shared__ __align__(16) char LDS[LDS_BYTES];
    const int rg = blockIdx.x, rel = blockIdx.y, sl = blockIdx.z;
    const float* S = (rel == 0) ? S0 : (rel == 1 ? S1 : S2);
    const unsigned short* Mtr = Mt + (size_t)rel * D * N;
    const int tid = threadIdx.x;
    const int lane = tid & 63, wave = tid >> 6;
    const int row = tid >> 2, q = tid & 3;      // e-phase: 4 lanes per row, 8 cols each
    const int j0 = sl * JLEN;

    // per-thread pre-swizzled global sources for the DMAs
    const int srow = tid >> 3, sslot = tid & 7;
    const int sx = (sslot ^ (srow & 7)) * 4;               // 4 floats per 16B slot
    const float* s0p = S + (size_t)(rg * 64 + srow) * N + j0 + sx;
    const float* s1p = S + (size_t)(rg * 64 + 32 + srow) * N + j0 + sx;
    const unsigned short* mtp = Mtr + (size_t)(tid & 63) * N + j0 + (tid >> 6) * 8;
    // wave-uniform LDS DMA bases
    char* sldsw = LDS + S_OFF + wave * 1024;
    char* mldsw = LDS + MT_OFF + wave * 1024;

#define ISSUE(cc, bb) do {                                         \
        gld16_nt(s0p + (cc) * CH, sldsw + (bb) * 8192);            \
        gld16_nt(s1p + (cc) * CH, sldsw + (bb) * 8192 + 4096);     \
        gld16(mtp + (cc) * CH, mldsw + (bb) * 4096);               \
    } while (0)

    // prologue: stage scale slice, then DMA chunks 0 and 1
    for (int k = tid; k < JLEN; k += 256)
        *(float*)(LDS + SCL_OFF + k * 4) = scale[rel * N + j0 + k];
    asm volatile("" ::: "memory");
    ISSUE(0, 0);
    ISSUE(1, 1);
    lds_barrier();   // scl visible; 6 DMAs in flight

    const int wbase = wave * 16;
    const int lrow  = lane & 15;   // A-row / B-col / C-col within tile
    const int lk    = lane >> 4;   // k-group / C row-group
    float l = 0.f;
    f32x4 acc[4];
    #pragma unroll
    for (int ct = 0; ct < 4; ++ct) {
        acc[ct][0] = 0.f; acc[ct][1] = 0.f; acc[ct][2] = 0.f; acc[ct][3] = 0.f;
    }

    int bc = 0;   // LDS buffer of chunk c
    for (int c = 0; c < NCHUNK; ++c) {
        // wait: chunk c landed (3 youngest = chunk c+1 still in flight)
        if (c < NCHUNK - 1) asm volatile("s_waitcnt vmcnt(3)" ::: "memory");
        else                asm volatile("s_waitcnt vmcnt(0)" ::: "memory");
        plain_barrier();   // all waves' chunk-c DMAs landed; buf (c-1)%3 readers done

        // issue chunk c+2 into buf (c+2)%3 == (c-1)%3 (max cover: ~2 iterations)
        if (c + 2 < NCHUNK) {
            int bn = bc + 2; if (bn >= 3) bn -= 3;
            ISSUE(c + 2, bn);
        }

        // ---- e-phase: read S tile (un-swizzle by XOR), exp, pack bf16 -> E ----
        {
            const char* sb = LDS + S_OFF + bc * 8192;
            const int r7 = row & 7;
            const f32x4 va = *(const f32x4*)(sb + row * 128 + (((2 * q)     ^ r7) << 4));
            const f32x4 vb = *(const f32x4*)(sb + row * 128 + (((2 * q + 1) ^ r7) << 4));
            const f32x4 ca = *(const f32x4*)(LDS + SCL_OFF + c * 128 + q * 32);
            const f32x4 cb = *(const f32x4*)(LDS + SCL_OFF + c * 128 + q * 32 + 16);
            float e[8];
            e[0] = __expf(fmaf(va[0], ca[0], -SH));
            e[1] = __expf(fmaf(va[1], ca[1], -SH));
            e[2] = __expf(fmaf(va[2], ca[2], -SH));
            e[3] = __expf(fmaf(va[3], ca[3], -SH));
            e[4] = __expf(fmaf(vb[0], cb[0], -SH));
            e[5] = __expf(fmaf(vb[1], cb[1], -SH));
            e[6] = __expf(fmaf(vb[2], cb[2], -SH));
            e[7] = __expf(fmaf(vb[3], cb[3], -SH));
            #pragma unroll
            for (int k = 0; k < 8; ++k) l += e[k];
            union { unsigned short h[8]; uint4 v; } pk;
            #pragma unroll
            for (int k = 0; k < 8; ++k) pk.h[k] = f2bf(e[k]);
            // E slot = q*64 + (row ^ 2q): conflict-free write and read
            *(uint4*)(LDS + E_OFF + ((q * 64 + (row ^ (2 * q))) << 4)) = pk.v;
        }

        lds_barrier();   // E visible; DMAs stay in flight

        // ---- MFMA: 4x mfma_16x16x32, conflict-free fragment reads ----
        {
            const char* mb = LDS + MT_OFF + bc * 4096;
            const bf16x8 a = *(const bf16x8*)(
                LDS + E_OFF + ((lk * 64 + ((wbase + lrow) ^ (2 * lk))) << 4));
            #pragma unroll
            for (int ct = 0; ct < 4; ++ct) {
                const bf16x8 b = *(const bf16x8*)(mb + ((lk * 64 + ct * 16 + lrow) << 4));
                acc[ct] = __builtin_amdgcn_mfma_f32_16x16x32_bf16(a, b, acc[ct], 0, 0, 0);
            }
        }
        // no trailing barrier: next iter's top barrier orders buffer reuse

        bc = bc + 1; if (bc == 3) bc = 0;
    }
#undef ISSUE

    // ---- epilogue: repack partials into LDS (S buf 0 region, now dead) ----
    unsigned short* R = (unsigned short*)LDS;
    #pragma unroll
    for (int ct = 0; ct < 4; ++ct)
        #pragma unroll
        for (int r = 0; r < 4; ++r) {
            const int ri = wbase + lk * 4 + r;   // C/D: row=(lane>>4)*4+reg
            R[ri * 64 + ct * 16 + lrow] = f2bf(acc[ct][r]);
        }
    lds_barrier();
    const size_t pbase = (size_t)((rel * 64 + rg) * NSLICE + sl);
    unsigned short* up = Up + pbase * 4096;
    {
        const uint4* src = (const uint4*)R;
        uint4*       dst = (uint4*)up;
        dst[tid]       = src[tid];
        dst[256 + tid] = src[256 + tid];
    }
    l += __shfl_xor(l, 1);
    l += __shfl_xor(l, 2);
    if (q == 0) lp[pbase * 64 + row] = l;
}

// ---------------- Kernel C: combine partials + residual + linear(W3) + leaky-relu ----------------
__device__ __forceinline__ float combine_row(
    const unsigned short* __restrict__ Up, const float* __restrict__ lp,
    int rel, int i, int d)
{
    const int rg = i >> 6, r = i & 63;
    const int base = (rel * 64 + rg) * NSLICE;
    float lt = 0.f, u = 0.f;
    #pragma unroll
    for (int p = 0; p < NSLICE; ++p) {
        lt += lp[(base + p) * 64 + r];
        u  += bf2f(Up[(size_t)(base + p) * 4096 + r * 64 + d]);
    }
    return u / lt;   // fixed shift cancels; lt > 0 always
}

__global__ __launch_bounds__(256) void final_kernel(
    const float* __restrict__ embed,
    const unsigned short* __restrict__ Up, const float* __restrict__ lp,
    const float* __restrict__ W3, const float* __restrict__ b3,
    float* __restrict__ out)
{
    __shared__ float Wl[D][D + 1];
    __shared__ float xs[4][D];
    const int tid = threadIdx.x;
    for (int idx = tid; idx < D * D; idx += 256)
        Wl[idx >> 6][idx & 63] = W3[idx];
    const int w = tid >> 6, d = tid & 63;
    const int g = blockIdx.x * 4 + w;   // 0..8191

    float x = embed[(size_t)g * D + d];
    if (g < N) {
        x += combine_row(Up, lp, 0, g, d);
        x += combine_row(Up, lp, 1, g, d);
    } else {
        x += combine_row(Up, lp, 2, g - N, d);
    }
    xs[w][d] = x;
    __syncthreads();
    float o = b3[d];
    #pragma unroll 8
    for (int k = 0; k < D; ++k) o += xs[w][k] * Wl[d][k];
    o = (o > 0.f) ? o : 0.2f * o;
    out[(size_t)g * D + d] = o;
}

extern "C" void kernel_launch(void* const* d_in, const int* in_sizes, int n_in,
                              void* d_out, int out_size, void* d_ws, size_t ws_size,
                              hipStream_t stream)
{
    const float* embed = (const float*)d_in[0];
    // d_in[1..3] = adj_* (unused by the reference)
    const float* Sc   = (const float*)d_in[4];
    const float* Si   = (const float*)d_in[5];
    const float* Ss   = (const float*)d_in[6];
    const float* degd = (const float*)d_in[7];
    const float* degt = (const float*)d_in[8];
    const float* W1 = (const float*)d_in[9];
    const float* b1 = (const float*)d_in[10];
    const float* W2 = (const float*)d_in[11];
    const float* b2 = (const float*)d_in[12];
    const float* W3 = (const float*)d_in[13];
    const float* b3 = (const float*)d_in[14];
    float* out = (float*)d_out;

    // ws layout:
    //   scale: 3*N              = 12288 f32
    //   lp:    3*64*NSLICE*64   = 49152 f32
    //   Mt:    3*D*N            = 786432 ushort
    //   Up:    3*64*NSLICE*4096 = 3145728 ushort          total ~8.1 MB
    float* ws    = (float*)d_ws;
    float* scale = ws;
    float* lp    = ws + 12288;
    unsigned short* Mt = (unsigned short*)(lp + 49152);
    unsigned short* Up = Mt + 786432;

    prep_kernel<<<dim3(N / 4, 3), 256, 0, stream>>>(
        embed, degd, degt, W1, b1, W2, b2, W3, b3, scale, Mt);
    attn_kernel<<<dim3(64, 3, NSLICE), 256, 0, stream>>>(
        Sc, Si, Ss, scale, Mt, Up, lp);
    final_kernel<<<dim3(2 * N / 4), 256, 0, stream>>>(
        embed, Up, lp, W3, b3, out);
}

// Round 14
// 58.984 us; speedup vs baseline: 1.3530x; 1.2047x over previous
//
#include <hip/hip_runtime.h>
#include <math.h>

#define N 4096
#define D 64
#define ROWS 128          // rows per block (halves Mt re-read traffic vs 64)
#define NSLICE 8
#define JLEN 512          // N / NSLICE
#define CH 32             // j-chunk per iteration
#define NCHUNK 16         // JLEN / CH
#define SH 44.0f          // fixed softmax shift: exp(logit - 44); cancels in u/l

// LDS byte map (50 KB -> 3 blocks/CU):
//   S:   2 bufs x 16 KB fp32 [128 rows][8 slots of 16B], slot ^= (row&7) via global pre-swizzle
//   Mt:  2 bufs x 4 KB  bf16, byte = kg*1024 + d*16
//   E:   8 KB           bf16, byte = kg*2048 + ((row ^ 2kg)<<4)
//   scl: 2 KB           fp32 scale slice
#define S_OFF   0
#define MT_OFF  32768
#define E_OFF   40960
#define SCL_OFF 49152
#define LDS_BYTES 51200

typedef short bf16x8 __attribute__((ext_vector_type(8)));
typedef float f32x4  __attribute__((ext_vector_type(4)));

__device__ __forceinline__ unsigned short f2bf(float x) {   // RNE f32->bf16
    unsigned int u = __float_as_uint(x);
    u += 0x7FFFu + ((u >> 16) & 1u);
    return (unsigned short)(u >> 16);
}
__device__ __forceinline__ float bf2f(unsigned short h) {
    return __uint_as_float(((unsigned int)h) << 16);
}

// async global->LDS DMA, 16B per lane; LDS dest wave-uniform base + lane*16.
__device__ __forceinline__ void gld16(const void* g, void* l) {
    __builtin_amdgcn_global_load_lds(
        (const __attribute__((address_space(1))) void*)g,
        (__attribute__((address_space(3))) void*)l,
        16, 0, 0);
}

// Barrier that waits only LDS ops; global/DMA loads stay in flight across it.
__device__ __forceinline__ void lds_barrier() {
    asm volatile("s_waitcnt lgkmcnt(0)" ::: "memory");
    __builtin_amdgcn_s_barrier();
    asm volatile("" ::: "memory");
}
__device__ __forceinline__ void plain_barrier() {
    asm volatile("" ::: "memory");
    __builtin_amdgcn_s_barrier();
    asm volatile("" ::: "memory");
}

// ---------------- Kernel A: per-row scale + Mt[d][j] = bf16(linear(msg)) ----------------
__global__ __launch_bounds__(256) void prep_kernel(
    const float* __restrict__ embed,
    const float* __restrict__ degd, const float* __restrict__ degt,
    const float* __restrict__ W1, const float* __restrict__ b1,
    const float* __restrict__ W2, const float* __restrict__ b2,
    const float* __restrict__ W3, const float* __restrict__ b3,
    float* __restrict__ scale, unsigned short* __restrict__ Mt)
{
    const int rel = blockIdx.y;
    const float* W  = (rel == 0) ? W1 : (rel == 1 ? W2 : W3);
    const float* bb = (rel == 0) ? b1 : (rel == 1 ? b2 : b3);
    __shared__ float Wl[D][D + 1];
    __shared__ float xr[4][D];
    __shared__ unsigned short ot[4][D];   // staged Mt tile for coalesced write
    const int tid = threadIdx.x;
    for (int idx = tid; idx < D * D; idx += 256)
        Wl[idx >> 6][idx & 63] = W[idx];
    const int w = tid >> 6, d = tid & 63;
    const int i0 = blockIdx.x * 4;
    const int i = i0 + w;

    float msg, term, xsrc, dga, dgb;
    if (rel == 0) {
        float s = embed[(size_t)i * D + d];
        msg = s + s * s; term = s * msg; xsrc = msg;
        dga = degd[i]; dgb = degd[i];
    } else if (rel == 1) {
        float s = embed[(size_t)i * D + d];
        float t = embed[(size_t)(N + i) * D + d];
        msg = t + s * t; term = s * msg; xsrc = msg;
        dga = degd[i]; dgb = degt[i];
    } else {
        float t = embed[(size_t)(N + i) * D + d];
        msg = t + t * t; term = t * msg; xsrc = t;   // similar uses linear(task)!
        dga = degt[i]; dgb = degt[i];
    }
    float dot = term;
    #pragma unroll
    for (int mm = 1; mm < 64; mm <<= 1) dot += __shfl_xor(dot, mm);
    if (d == 0)
        scale[rel * N + i] = dot / (sqrtf(dga * dgb + 1e-8f) * 8.0f);  // sqrt(D)=8

    xr[w][d] = xsrc;
    __syncthreads();
    float o = bb[d];
    #pragma unroll 8
    for (int k = 0; k < D; ++k) o += xr[w][k] * Wl[d][k];
    ot[w][d] = f2bf(o);
    __syncthreads();
    // Mt[d][i0..i0+3]: 8B runs, one thread per d (wave 0 only)
    if (tid < 64) {
        union { unsigned short h[4]; uint2 v; } t;
        t.h[0] = ot[0][tid]; t.h[1] = ot[1][tid];
        t.h[2] = ot[2][tid]; t.h[3] = ot[3][tid];
        *(uint2*)&Mt[((size_t)rel * D + tid) * N + i0] = t.v;
    }
}

// ------------- Kernel B: fixed-shift softmax x (att @ M) via bf16 MFMA -------------
// grid (32 rowgroups of 128, 3 rels, NSLICE slices), block 256 (4 waves), 3 blocks/CU.
// 128-row blocks halve the Mt re-read request traffic (the measured binder).
// DMA staging, double-buffered S/Mt, FIFO-exact counted vmcnt(4).
__global__ __launch_bounds__(256, 3) void attn_kernel(
    const float* __restrict__ S0, const float* __restrict__ S1, const float* __restrict__ S2,
    const float* __restrict__ scale, const unsigned short* __restrict__ Mt,
    unsigned short* __restrict__ Up, float* __restrict__ lp)
{
    __shared__ __align__(16) char LDS[LDS_BYTES];
    const int rg = blockIdx.x, rel = blockIdx.y, sl = blockIdx.z;
    const float* S = (rel == 0) ? S0 : (rel == 1 ? S1 : S2);
    const unsigned short* Mtr = Mt + (size_t)rel * D * N;
    const int tid = threadIdx.x;
    const int lane = tid & 63, wave = tid >> 6;
    const int row = tid >> 1, q = tid & 1;      // e-phase: 2 lanes/row, 16 cols each
    const int j0 = sl * JLEN;

    // S DMA: per wave 4 insts; inst j covers rows wave*32+j*8 .. +8.
    // row-in-group = lane>>3 == row&7 (group bases are multiples of 8) -> pre-swizzle slot.
    const int sr8 = lane >> 3, sslot = lane & 7;
    const int sgx = (sslot ^ sr8) * 4;   // floats
    const float* spb = S + (size_t)(rg * ROWS + wave * 32 + sr8) * N + j0 + sgx;
    // Mt DMA: wave w loads k-octet plane w; d = lane.
    const unsigned short* mtp = Mtr + (size_t)lane * N + j0 + wave * 8;
    char* sldsw = LDS + S_OFF + wave * 4096;   // + j*1024 + buf*16384
    char* mldsw = LDS + MT_OFF + wave * 1024;  // + buf*4096

#define ISSUE_S(cc, bb) do {                                                   \
        gld16(spb + (size_t)0 * 8 * N + (cc) * CH, sldsw + (bb) * 16384);      \
        gld16(spb + (size_t)1 * 8 * N + (cc) * CH, sldsw + (bb) * 16384 + 1024); \
        gld16(spb + (size_t)2 * 8 * N + (cc) * CH, sldsw + (bb) * 16384 + 2048); \
        gld16(spb + (size_t)3 * 8 * N + (cc) * CH, sldsw + (bb) * 16384 + 3072); \
    } while (0)
#define ISSUE_M(cc, bb) gld16(mtp + (cc) * CH, mldsw + (bb) * 4096)

    // prologue: stage scale slice; FIFO queue [S0(4), M0(1), S1(4)]
    for (int k = tid; k < JLEN; k += 256)
        *(float*)(LDS + SCL_OFF + k * 4) = scale[rel * N + j0 + k];
    asm volatile("" ::: "memory");
    ISSUE_S(0, 0);
    ISSUE_M(0, 0);
    ISSUE_S(1, 1);
    lds_barrier();   // scl visible; 9 DMAs in flight

    const int lrow = lane & 15;   // A-row / B-col / C-col within tile
    const int lk   = lane >> 4;   // k-octet / C row-group
    float l = 0.f;
    f32x4 acc[2][4];
    #pragma unroll
    for (int t = 0; t < 2; ++t)
        #pragma unroll
        for (int ct = 0; ct < 4; ++ct) {
            acc[t][ct][0] = 0.f; acc[t][ct][1] = 0.f;
            acc[t][ct][2] = 0.f; acc[t][ct][3] = 0.f;
        }

    #pragma unroll
    for (int c = 0; c < NCHUNK; ++c) {
        // FIFO-exact: outstanding = [S(c)(4), M(c)(1), S(c+1)(4)]; drain chunk c's 5
        if (c < NCHUNK - 1) asm volatile("s_waitcnt vmcnt(4)" ::: "memory");
        else                asm volatile("s_waitcnt vmcnt(0)" ::: "memory");
        plain_barrier();   // chunk c landed everywhere; iter c-1 MFMA reads done

        // issue M(c+1) into Mt buf (c+1)&1 (its chunk-(c-1) readers done at this barrier)
        if (c + 1 < NCHUNK) ISSUE_M(c + 1, (c + 1) & 1);

        // ---- e-phase: 16 cols/thread, exp, pack, 2x ds_write_b128 ----
        {
            const char* sb = LDS + S_OFF + (c & 1) * 16384 + row * 128;
            const int r7 = row & 7;
            const f32x4 s0 = *(const f32x4*)(sb + (((q * 4 + 0) ^ r7) << 4));
            const f32x4 s1 = *(const f32x4*)(sb + (((q * 4 + 1) ^ r7) << 4));
            const f32x4 s2 = *(const f32x4*)(sb + (((q * 4 + 2) ^ r7) << 4));
            const f32x4 s3 = *(const f32x4*)(sb + (((q * 4 + 3) ^ r7) << 4));
            const char* cb = LDS + SCL_OFF + c * 128 + q * 64;
            const f32x4 c0 = *(const f32x4*)(cb);
            const f32x4 c1 = *(const f32x4*)(cb + 16);
            const f32x4 c2 = *(const f32x4*)(cb + 32);
            const f32x4 c3 = *(const f32x4*)(cb + 48);
            float e[16];
            #pragma unroll
            for (int u = 0; u < 4; ++u) {
                e[u]      = __expf(fmaf(s0[u], c0[u], -SH));
                e[4 + u]  = __expf(fmaf(s1[u], c1[u], -SH));
                e[8 + u]  = __expf(fmaf(s2[u], c2[u], -SH));
                e[12 + u] = __expf(fmaf(s3[u], c3[u], -SH));
            }
            #pragma unroll
            for (int k = 0; k < 16; ++k) l += e[k];
            union { unsigned short h[8]; uint4 v; } p0, p1;
            #pragma unroll
            for (int k = 0; k < 8; ++k) { p0.h[k] = f2bf(e[k]); p1.h[k] = f2bf(e[8 + k]); }
            const int kgA = 2 * q, kgB = 2 * q + 1;
            *(uint4*)(LDS + E_OFF + kgA * 2048 + ((row ^ (2 * kgA)) << 4)) = p0.v;
            *(uint4*)(LDS + E_OFF + kgB * 2048 + ((row ^ (2 * kgB)) << 4)) = p1.v;
        }

        lds_barrier();   // E visible; all waves' S-buf(c&1) reads done

        // issue S(c+2) into S buf c&1 (just fully read)
        if (c + 2 < NCHUNK) ISSUE_S(c + 2, c & 1);

        // ---- MFMA: 2 row-tiles x 4 col-tiles, K=32 ----
        {
            const char* mb = LDS + MT_OFF + (c & 1) * 4096 + lk * 1024;
            const int ra0 = wave * 32 + lrow, ra1 = wave * 32 + 16 + lrow;
            const bf16x8 a0 = *(const bf16x8*)(
                LDS + E_OFF + lk * 2048 + ((ra0 ^ (2 * lk)) << 4));
            const bf16x8 a1 = *(const bf16x8*)(
                LDS + E_OFF + lk * 2048 + ((ra1 ^ (2 * lk)) << 4));
            #pragma unroll
            for (int ct = 0; ct < 4; ++ct) {
                const bf16x8 b = *(const bf16x8*)(mb + ((ct * 16 + lrow) << 4));
                acc[0][ct] = __builtin_amdgcn_mfma_f32_16x16x32_bf16(a0, b, acc[0][ct], 0, 0, 0);
                acc[1][ct] = __builtin_amdgcn_mfma_f32_16x16x32_bf16(a1, b, acc[1][ct], 0, 0, 0);
            }
        }
        // no trailing barrier: next iter's top barrier orders buffer reuse
    }
#undef ISSUE_S
#undef ISSUE_M

    // ---- epilogue: repack 128x64 bf16 tile into S-buf region (dead), wide stores ----
    unsigned short* R = (unsigned short*)LDS;
    #pragma unroll
    for (int t = 0; t < 2; ++t)
        #pragma unroll
        for (int ct = 0; ct < 4; ++ct)
            #pragma unroll
            for (int r = 0; r < 4; ++r) {
                const int ri = wave * 32 + t * 16 + lk * 4 + r;  // C/D: row=(lane>>4)*4+reg
                R[ri * 64 + ct * 16 + lrow] = f2bf(acc[t][ct][r]);
            }
    lds_barrier();
    const size_t pbase = (size_t)((rel * 32 + rg) * NSLICE + sl);
    unsigned short* up = Up + pbase * 8192;
    {
        const uint4* src = (const uint4*)R;
        uint4*       dst = (uint4*)up;
        dst[tid]       = src[tid];
        dst[256 + tid] = src[256 + tid];
        dst[512 + tid] = src[512 + tid];
        dst[768 + tid] = src[768 + tid];
    }
    l += __shfl_xor(l, 1);   // q-pair reduce (2 lanes per row)
    if (q == 0) lp[pbase * ROWS + row] = l;
}

// ---------------- Kernel C: combine partials + residual + linear(W3) + leaky-relu ----------------
__device__ __forceinline__ float combine_row(
    const unsigned short* __restrict__ Up, const float* __restrict__ lp,
    int rel, int i, int d)
{
    const int rt = i >> 7, r = i & 127;
    const int base = (rel * 32 + rt) * NSLICE;
    float lt = 0.f, u = 0.f;
    #pragma unroll
    for (int p = 0; p < NSLICE; ++p) {
        lt += lp[(base + p) * ROWS + r];
        u  += bf2f(Up[(size_t)(base + p) * 8192 + r * 64 + d]);
    }
    return u / lt;   // fixed shift cancels; lt > 0 always
}

__global__ __launch_bounds__(256) void final_kernel(
    const float* __restrict__ embed,
    const unsigned short* __restrict__ Up, const float* __restrict__ lp,
    const float* __restrict__ W3, const float* __restrict__ b3,
    float* __restrict__ out)
{
    __shared__ float Wl[D][D + 1];
    __shared__ float xs[4][D];
    const int tid = threadIdx.x;
    for (int idx = tid; idx < D * D; idx += 256)
        Wl[idx >> 6][idx & 63] = W3[idx];
    const int w = tid >> 6, d = tid & 63;
    const int g = blockIdx.x * 4 + w;   // 0..8191

    float x = embed[(size_t)g * D + d];
    if (g < N) {
        x += combine_row(Up, lp, 0, g, d);
        x += combine_row(Up, lp, 1, g, d);
    } else {
        x += combine_row(Up, lp, 2, g - N, d);
    }
    xs[w][d] = x;
    __syncthreads();
    float o = b3[d];
    #pragma unroll 8
    for (int k = 0; k < D; ++k) o += xs[w][k] * Wl[d][k];
    o = (o > 0.f) ? o : 0.2f * o;
    out[(size_t)g * D + d] = o;
}

extern "C" void kernel_launch(void* const* d_in, const int* in_sizes, int n_in,
                              void* d_out, int out_size, void* d_ws, size_t ws_size,
                              hipStream_t stream)
{
    const float* embed = (const float*)d_in[0];
    // d_in[1..3] = adj_* (unused by the reference)
    const float* Sc   = (const float*)d_in[4];
    const float* Si   = (const float*)d_in[5];
    const float* Ss   = (const float*)d_in[6];
    const float* degd = (const float*)d_in[7];
    const float* degt = (const float*)d_in[8];
    const float* W1 = (const float*)d_in[9];
    const float* b1 = (const float*)d_in[10];
    const float* W2 = (const float*)d_in[11];
    const float* b2 = (const float*)d_in[12];
    const float* W3 = (const float*)d_in[13];
    const float* b3 = (const float*)d_in[14];
    float* out = (float*)d_out;

    // ws layout:
    //   scale: 3*N                 = 12288 f32
    //   lp:    3*32*NSLICE*128     = 98304 f32
    //   Mt:    3*D*N               = 786432 ushort
    //   Up:    3*32*NSLICE*8192    = 6291456 ushort        total ~14.6 MB
    float* ws    = (float*)d_ws;
    float* scale = ws;
    float* lp    = ws + 12288;
    unsigned short* Mt = (unsigned short*)(lp + 98304);
    unsigned short* Up = Mt + 786432;

    prep_kernel<<<dim3(N / 4, 3), 256, 0, stream>>>(
        embed, degd, degt, W1, b1, W2, b2, W3, b3, scale, Mt);
    attn_kernel<<<dim3(N / ROWS, 3, NSLICE), 256, 0, stream>>>(
        Sc, Si, Ss, scale, Mt, Up, lp);
    final_kernel<<<dim3(2 * N / 4), 256, 0, stream>>>(
        embed, Up, lp, W3, b3, out);
}

// Round 15
// 58.398 us; speedup vs baseline: 1.3665x; 1.0100x over previous
//
#include <hip/hip_runtime.h>
#include <math.h>

#define N 4096
#define D 64
#define ROWS 128          // rows per block (wave owns 32)
#define NSLICE 8
#define JLEN 512          // N / NSLICE
#define CH 32             // j-chunk per iteration
#define NCHUNK 16         // JLEN / CH
#define SH 44.0f          // fixed softmax shift: exp(logit - 44); cancels in u/l

// LDS byte map (50 KB -> 3 blocks/CU):
//   S:   per-wave 2 bufs x 4 KB  fp32 [32 rows][8 slots], slot ^= (row&7) via global pre-swizzle
//   Mt:  2 bufs x 4 KB  bf16, byte = kg*1024 + d*16   (cross-wave; the one barrier/chunk)
//   E:   per-wave 2 KB  bf16, byte = kg*512 + r*16    (wave-local, bank-even)
//   scl: 2 KB           fp32 scale slice
#define S_OFF   0
#define MT_OFF  32768
#define E_OFF   40960
#define SCL_OFF 49152
#define LDS_BYTES 51200

typedef short bf16x8 __attribute__((ext_vector_type(8)));
typedef float f32x4  __attribute__((ext_vector_type(4)));

__device__ __forceinline__ unsigned short f2bf(float x) {   // RNE f32->bf16
    unsigned int u = __float_as_uint(x);
    u += 0x7FFFu + ((u >> 16) & 1u);
    return (unsigned short)(u >> 16);
}
__device__ __forceinline__ float bf2f(unsigned short h) {
    return __uint_as_float(((unsigned int)h) << 16);
}

// async global->LDS DMA, 16B per lane; LDS dest wave-uniform base + lane*16.
__device__ __forceinline__ void gld16(const void* g, void* l) {
    __builtin_amdgcn_global_load_lds(
        (const __attribute__((address_space(1))) void*)g,
        (__attribute__((address_space(3))) void*)l,
        16, 0, 0);
}

__device__ __forceinline__ void lds_barrier() {
    asm volatile("s_waitcnt lgkmcnt(0)" ::: "memory");
    __builtin_amdgcn_s_barrier();
    asm volatile("" ::: "memory");
}

// ---------------- Kernel A: per-row scale + Mt[d][j] = bf16(linear(msg)) ----------------
__global__ __launch_bounds__(256) void prep_kernel(
    const float* __restrict__ embed,
    const float* __restrict__ degd, const float* __restrict__ degt,
    const float* __restrict__ W1, const float* __restrict__ b1,
    const float* __restrict__ W2, const float* __restrict__ b2,
    const float* __restrict__ W3, const float* __restrict__ b3,
    float* __restrict__ scale, unsigned short* __restrict__ Mt)
{
    const int rel = blockIdx.y;
    const float* W  = (rel == 0) ? W1 : (rel == 1 ? W2 : W3);
    const float* bb = (rel == 0) ? b1 : (rel == 1 ? b2 : b3);
    __shared__ float Wl[D][D + 1];
    __shared__ float xr[4][D];
    __shared__ unsigned short ot[4][D];   // staged Mt tile for coalesced write
    const int tid = threadIdx.x;
    for (int idx = tid; idx < D * D; idx += 256)
        Wl[idx >> 6][idx & 63] = W[idx];
    const int w = tid >> 6, d = tid & 63;
    const int i0 = blockIdx.x * 4;
    const int i = i0 + w;

    float msg, term, xsrc, dga, dgb;
    if (rel == 0) {
        float s = embed[(size_t)i * D + d];
        msg = s + s * s; term = s * msg; xsrc = msg;
        dga = degd[i]; dgb = degd[i];
    } else if (rel == 1) {
        float s = embed[(size_t)i * D + d];
        float t = embed[(size_t)(N + i) * D + d];
        msg = t + s * t; term = s * msg; xsrc = msg;
        dga = degd[i]; dgb = degt[i];
    } else {
        float t = embed[(size_t)(N + i) * D + d];
        msg = t + t * t; term = t * msg; xsrc = t;   // similar uses linear(task)!
        dga = degt[i]; dgb = degt[i];
    }
    float dot = term;
    #pragma unroll
    for (int mm = 1; mm < 64; mm <<= 1) dot += __shfl_xor(dot, mm);
    if (d == 0)
        scale[rel * N + i] = dot / (sqrtf(dga * dgb + 1e-8f) * 8.0f);  // sqrt(D)=8

    xr[w][d] = xsrc;
    __syncthreads();
    float o = bb[d];
    #pragma unroll 8
    for (int k = 0; k < D; ++k) o += xr[w][k] * Wl[d][k];
    ot[w][d] = f2bf(o);
    __syncthreads();
    // Mt[d][i0..i0+3]: 8B runs, one thread per d (wave 0 only)
    if (tid < 64) {
        union { unsigned short h[4]; uint2 v; } t;
        t.h[0] = ot[0][tid]; t.h[1] = ot[1][tid];
        t.h[2] = ot[2][tid]; t.h[3] = ot[3][tid];
        *(uint2*)&Mt[((size_t)rel * D + tid) * N + i0] = t.v;
    }
}

// ------------- Kernel B: fixed-shift softmax x (att @ M) via bf16 MFMA -------------
// 1D grid 768 with XCD-aware decode (32 blocks sharing an Mt slice -> one XCD).
// Wave-local S staging (per-wave DMA + per-wave counted vmcnt, NO barrier for S),
// wave-local E, wave-local epilogue. ONE barrier per chunk (Mt plane visibility).
__global__ __launch_bounds__(256, 3) void attn_kernel(
    const float* __restrict__ S0, const float* __restrict__ S1, const float* __restrict__ S2,
    const float* __restrict__ scale, const unsigned short* __restrict__ Mt,
    unsigned short* __restrict__ Up, float* __restrict__ lp)
{
    __shared__ __align__(16) char LDS[LDS_BYTES];
    // XCD-aware decode: xcd = bid%8 (dispatch heuristic); 3 (rel,sl) pairs per XCD;
    // the 32 rowgroups of a pair are contiguous on that XCD -> Mt slice L2-resident.
    const int bid = blockIdx.x;
    const int xcd = bid & 7, idx = bid >> 3;          // idx 0..95
    const int pair = xcd * 3 + (idx >> 5);            // 0..23
    const int rg = idx & 31;
    const int rel = pair >> 3, sl = pair & 7;

    const float* S = (rel == 0) ? S0 : (rel == 1 ? S1 : S2);
    const unsigned short* Mtr = Mt + (size_t)rel * D * N;
    const int tid = threadIdx.x;
    const int lane = tid & 63, wave = tid >> 6;
    const int j0 = sl * JLEN;

    // S DMA (wave-local): inst j covers the wave's rows j*8..j*8+7, 32 cols fp32.
    const int sr8 = lane >> 3, sslot = lane & 7;
    const int sgx = (sslot ^ sr8) * 4;   // pre-swizzled global col (floats)
    const float* spb = S + (size_t)(rg * ROWS + wave * 32 + sr8) * N + j0 + sgx;
    // Mt DMA: wave w loads k-octet plane w; d = lane.
    const unsigned short* mtp = Mtr + (size_t)lane * N + j0 + wave * 8;
    char* sldsw = LDS + S_OFF + wave * 8192;   // + buf*4096 + j*1024
    char* mldsw = LDS + MT_OFF + wave * 1024;  // + buf*4096

#define ISSUE_S(cc, bb) do {                                                     \
        gld16(spb + (size_t)0 * 8 * N + (cc) * CH, sldsw + (bb) * 4096);         \
        gld16(spb + (size_t)1 * 8 * N + (cc) * CH, sldsw + (bb) * 4096 + 1024);  \
        gld16(spb + (size_t)2 * 8 * N + (cc) * CH, sldsw + (bb) * 4096 + 2048);  \
        gld16(spb + (size_t)3 * 8 * N + (cc) * CH, sldsw + (bb) * 4096 + 3072);  \
    } while (0)
#define ISSUE_M(cc, bb) gld16(mtp + (cc) * CH, mldsw + (bb) * 4096)

    // prologue: per-wave FIFO [S0:4, M0:1, S1:4]; stage scale slice; one barrier
    ISSUE_S(0, 0);
    ISSUE_M(0, 0);
    ISSUE_S(1, 1);
    for (int k = tid; k < JLEN; k += 256)
        *(float*)(LDS + SCL_OFF + k * 4) = scale[rel * N + j0 + k];
    lds_barrier();   // scl visible; 9 DMAs in flight

    // e-phase map: lane -> (r = lane>>1 in 0..31, q = lane&1); 16 cols/thread
    const int r = lane >> 1, q = lane & 1;
    const int r7 = r & 7;
    // MFMA map
    const int lrow = lane & 15, lk = lane >> 4;
    char* Ew = LDS + E_OFF + wave * 2048;

    float l = 0.f;
    f32x4 acc[2][4];
    #pragma unroll
    for (int t = 0; t < 2; ++t)
        #pragma unroll
        for (int ct = 0; ct < 4; ++ct) {
            acc[t][ct][0] = 0.f; acc[t][ct][1] = 0.f;
            acc[t][ct][2] = 0.f; acc[t][ct][3] = 0.f;
        }

    #pragma unroll
    for (int c = 0; c < NCHUNK; ++c) {
        // per-wave FIFO: oldest 5 = [S(c):4, M(c):1]; keep the rest in flight
        if (c < NCHUNK - 1) asm volatile("s_waitcnt vmcnt(4)" ::: "memory");
        else                asm volatile("s_waitcnt vmcnt(0)" ::: "memory");
        lds_barrier();   // all waves' M(c) landed; all waves' MFMA(c-1) done

        // M(c+1) into buf (c+1)&1 (last read by MFMA(c-1), finished at barrier)
        if (c + 1 < NCHUNK) ISSUE_M(c + 1, (c + 1) & 1);

        // ---- e-phase: wave-local S buf -> exp -> wave-local E ----
        {
            const char* sb = sldsw + (c & 1) * 4096 + r * 128;
            const f32x4 s0 = *(const f32x4*)(sb + (((q * 4 + 0) ^ r7) << 4));
            const f32x4 s1 = *(const f32x4*)(sb + (((q * 4 + 1) ^ r7) << 4));
            const f32x4 s2 = *(const f32x4*)(sb + (((q * 4 + 2) ^ r7) << 4));
            const f32x4 s3 = *(const f32x4*)(sb + (((q * 4 + 3) ^ r7) << 4));
            const char* cb = LDS + SCL_OFF + c * 128 + q * 64;
            const f32x4 c0 = *(const f32x4*)(cb);
            const f32x4 c1 = *(const f32x4*)(cb + 16);
            const f32x4 c2 = *(const f32x4*)(cb + 32);
            const f32x4 c3 = *(const f32x4*)(cb + 48);
            float e[16];
            #pragma unroll
            for (int u = 0; u < 4; ++u) {
                e[u]      = __expf(fmaf(s0[u], c0[u], -SH));
                e[4 + u]  = __expf(fmaf(s1[u], c1[u], -SH));
                e[8 + u]  = __expf(fmaf(s2[u], c2[u], -SH));
                e[12 + u] = __expf(fmaf(s3[u], c3[u], -SH));
            }
            #pragma unroll
            for (int k = 0; k < 16; ++k) l += e[k];
            union { unsigned short h[8]; uint4 v; } p0, p1;
            #pragma unroll
            for (int k = 0; k < 8; ++k) { p0.h[k] = f2bf(e[k]); p1.h[k] = f2bf(e[8 + k]); }
            *(uint4*)(Ew + (2 * q)     * 512 + (r << 4)) = p0.v;
            *(uint4*)(Ew + (2 * q + 1) * 512 + (r << 4)) = p1.v;
        }

        // drain this wave's ds ops (S reads retired) -> safe to DMA-overwrite S buf
        asm volatile("s_waitcnt lgkmcnt(0)" ::: "memory");
        if (c + 2 < NCHUNK) ISSUE_S(c + 2, c & 1);

        // ---- MFMA: A wave-local E, B from Mt plane buf c&1 ----
        __builtin_amdgcn_s_setprio(1);
        {
            const char* mb = LDS + MT_OFF + (c & 1) * 4096 + lk * 1024;
            const bf16x8 a0 = *(const bf16x8*)(Ew + lk * 512 + (lrow << 4));
            const bf16x8 a1 = *(const bf16x8*)(Ew + lk * 512 + ((16 + lrow) << 4));
            #pragma unroll
            for (int ct = 0; ct < 4; ++ct) {
                const bf16x8 b = *(const bf16x8*)(mb + ((ct * 16 + lrow) << 4));
                acc[0][ct] = __builtin_amdgcn_mfma_f32_16x16x32_bf16(a0, b, acc[0][ct], 0, 0, 0);
                acc[1][ct] = __builtin_amdgcn_mfma_f32_16x16x32_bf16(a1, b, acc[1][ct], 0, 0, 0);
            }
        }
        __builtin_amdgcn_s_setprio(0);
        // no trailing barrier: S/E wave-local; Mt reuse ordered by next top barrier
    }
#undef ISSUE_S
#undef ISSUE_M

    // ---- wave-local epilogue: repack 32x64 tile into own S region, 1KB-run stores ----
    unsigned short* Rw = (unsigned short*)(sldsw);
    #pragma unroll
    for (int t = 0; t < 2; ++t)
        #pragma unroll
        for (int ct = 0; ct < 4; ++ct)
            #pragma unroll
            for (int rr = 0; rr < 4; ++rr) {
                const int ri = t * 16 + lk * 4 + rr;   // C/D: row=(lane>>4)*4+reg
                Rw[ri * 64 + ct * 16 + lrow] = f2bf(acc[t][ct][rr]);
            }
    asm volatile("s_waitcnt lgkmcnt(0)" ::: "memory");
    const size_t pbase = (size_t)((rel * 32 + rg) * NSLICE + sl);
    char* up = (char*)(Up + pbase * 8192) + wave * 4096;
    {
        const uint4* src = (const uint4*)((const char*)Rw + lane * 64);
        uint4*       dst = (uint4*)(up + lane * 64);
        dst[0] = src[0]; dst[1] = src[1]; dst[2] = src[2]; dst[3] = src[3];
    }
    l += __shfl_xor(l, 1);   // q-pair reduce (2 lanes per row)
    if (q == 0) lp[pbase * ROWS + wave * 32 + r] = l;
}

// ---------------- Kernel C: combine partials + residual + linear(W3) + leaky-relu ----------------
__device__ __forceinline__ float combine_row(
    const unsigned short* __restrict__ Up, const float* __restrict__ lp,
    int rel, int i, int d)
{
    const int rt = i >> 7, r = i & 127;
    const int base = (rel * 32 + rt) * NSLICE;
    float lt = 0.f, u = 0.f;
    #pragma unroll
    for (int p = 0; p < NSLICE; ++p) {
        lt += lp[(base + p) * ROWS + r];
        u  += bf2f(Up[(size_t)(base + p) * 8192 + r * 64 + d]);
    }
    return u / lt;   // fixed shift cancels; lt > 0 always
}

__global__ __launch_bounds__(256) void final_kernel(
    const float* __restrict__ embed,
    const unsigned short* __restrict__ Up, const float* __restrict__ lp,
    const float* __restrict__ W3, const float* __restrict__ b3,
    float* __restrict__ out)
{
    __shared__ float Wl[D][D + 1];
    __shared__ float xs[4][D];
    const int tid = threadIdx.x;
    for (int idx = tid; idx < D * D; idx += 256)
        Wl[idx >> 6][idx & 63] = W3[idx];
    const int w = tid >> 6, d = tid & 63;
    const int g = blockIdx.x * 4 + w;   // 0..8191

    float x = embed[(size_t)g * D + d];
    if (g < N) {
        x += combine_row(Up, lp, 0, g, d);
        x += combine_row(Up, lp, 1, g, d);
    } else {
        x += combine_row(Up, lp, 2, g - N, d);
    }
    xs[w][d] = x;
    __syncthreads();
    float o = b3[d];
    #pragma unroll 8
    for (int k = 0; k < D; ++k) o += xs[w][k] * Wl[d][k];
    o = (o > 0.f) ? o : 0.2f * o;
    out[(size_t)g * D + d] = o;
}

extern "C" void kernel_launch(void* const* d_in, const int* in_sizes, int n_in,
                              void* d_out, int out_size, void* d_ws, size_t ws_size,
                              hipStream_t stream)
{
    const float* embed = (const float*)d_in[0];
    // d_in[1..3] = adj_* (unused by the reference)
    const float* Sc   = (const float*)d_in[4];
    const float* Si   = (const float*)d_in[5];
    const float* Ss   = (const float*)d_in[6];
    const float* degd = (const float*)d_in[7];
    const float* degt = (const float*)d_in[8];
    const float* W1 = (const float*)d_in[9];
    const float* b1 = (const float*)d_in[10];
    const float* W2 = (const float*)d_in[11];
    const float* b2 = (const float*)d_in[12];
    const float* W3 = (const float*)d_in[13];
    const float* b3 = (const float*)d_in[14];
    float* out = (float*)d_out;

    // ws layout:
    //   scale: 3*N                 = 12288 f32
    //   lp:    3*32*NSLICE*128     = 98304 f32
    //   Mt:    3*D*N               = 786432 ushort
    //   Up:    3*32*NSLICE*8192    = 6291456 ushort        total ~14.6 MB
    float* ws    = (float*)d_ws;
    float* scale = ws;
    float* lp    = ws + 12288;
    unsigned short* Mt = (unsigned short*)(lp + 98304);
    unsigned short* Up = Mt + 786432;

    prep_kernel<<<dim3(N / 4, 3), 256, 0, stream>>>(
        embed, degd, degt, W1, b1, W2, b2, W3, b3, scale, Mt);
    attn_kernel<<<dim3((N / ROWS) * 3 * NSLICE), 256, 0, stream>>>(
        Sc, Si, Ss, scale, Mt, Up, lp);
    final_kernel<<<dim3(2 * N / 4), 256, 0, stream>>>(
        embed, Up, lp, W3, b3, out);
}